// Round 2
// baseline (343.251 us; speedup 1.0000x reference)
//
#include <hip/hip_runtime.h>
#include <hip/hip_bf16.h>
#include <cstdint>

typedef __bf16 bf16_t;
typedef __bf16 bf16x8 __attribute__((ext_vector_type(8)));
typedef float  f32x4  __attribute__((ext_vector_type(4)));
typedef int    i32x4  __attribute__((ext_vector_type(4)));

#define MFMA16(a, b, c) __builtin_amdgcn_mfma_f32_16x16x32_bf16((a), (b), (c), 0, 0, 0)

constexpr int BB = 8, CC = 384, NHH = 6, TT = 1024;

union U8 { uint4 u; bf16_t h[8]; };
union U2 { unsigned int u; bf16_t h[2]; };
union I4B { i32x4 i; bf16x8 v; };

static __device__ __forceinline__ void gload_lds16(const void* g, void* l) {
    __builtin_amdgcn_global_load_lds((const __attribute__((address_space(1))) void*)g,
                                     (__attribute__((address_space(3))) void*)l, 16, 0, 0);
}

// load 8 consecutive fp32 -> bf16x8
static __device__ __forceinline__ bf16x8 cvt8(const float* p) {
    f32x4 a = *(const f32x4*)p, b = *(const f32x4*)(p + 4);
    U8 o;
    #pragma unroll
    for (int j = 0; j < 4; ++j) { o.h[j] = (bf16_t)a[j]; o.h[4 + j] = (bf16_t)b[j]; }
    return *(bf16x8*)&o;
}

// ---------------------------------------------------------------------------
// K1: QKV projection from fp32 inputs (cast fused). Also computes
// vrs[b][o] = sum_t v[b][o][t] via shuffle-reduce + atomics (vrow fused).
//  q branch (og 0,1): store qT[b][t][o] (unscaled; head mix in fused_attn)
//  k branch (og 2,3): store kT[b][t][o]
//  v branch (og 4,5): store vm[b][o][t] + vrs atomics
// ---------------------------------------------------------------------------
__global__ __launch_bounds__(256) void qkv_kernel(
    const float* __restrict__ x,
    const float* __restrict__ Wq,
    const float* __restrict__ Wk,
    const float* __restrict__ Wv,
    bf16_t* __restrict__ qT,
    bf16_t* __restrict__ kT,
    bf16_t* __restrict__ vm,
    float*  __restrict__ vrs)
{
    const int og = blockIdx.x;        // 0,1:q  2,3:k  4,5:v
    const int tt = blockIdx.y;
    const int b  = blockIdx.z;
    const int t0 = tt * 64;
    const int tid  = threadIdx.x;
    const int lane = tid & 63;
    const int wid  = tid >> 6;
    const int quad = lane >> 4;
    const int l16  = lane & 15;

    __shared__ __align__(16) bf16_t xT[64][CC + 8];

    {
        const float* xb = x + (size_t)b * CC * TT;
        const int tq = tid & 7;
        const int cp = tid >> 3;
        #pragma unroll
        for (int pass = 0; pass < 6; ++pass) {
            const int c = (pass * 32 + cp) * 2;
            const float* r0 = xb + (size_t)c * TT + t0 + tq * 8;
            const float* r1 = r0 + TT;
            f32x4 a0 = *(const f32x4*)r0, a1 = *(const f32x4*)(r0 + 4);
            f32x4 b0 = *(const f32x4*)r1, b1 = *(const f32x4*)(r1 + 4);
            #pragma unroll
            for (int j = 0; j < 8; ++j) {
                U2 p;
                p.h[0] = (bf16_t)((j < 4) ? a0[j] : a1[j - 4]);
                p.h[1] = (bf16_t)((j < 4) ? b0[j] : b1[j - 4]);
                *(unsigned int*)&xT[tq * 8 + j][c] = p.u;
            }
        }
    }
    __syncthreads();

    const float* W = (og < 2) ? Wq : (og < 4) ? Wk : Wv;
    const int obase = (og & 1) * 192 + wid * 48;

    if (og < 4) {
        // A = W rows (m=o), B = xT rows (n=t)
        f32x4 acc[3][4];
        const f32x4 zero = {0.f, 0.f, 0.f, 0.f};
        #pragma unroll
        for (int mi = 0; mi < 3; ++mi)
            #pragma unroll
            for (int ni = 0; ni < 4; ++ni) acc[mi][ni] = zero;

        for (int k0 = 0; k0 < CC; k0 += 32) {
            bf16x8 afr[3];
            #pragma unroll
            for (int mi = 0; mi < 3; ++mi)
                afr[mi] = cvt8(W + (size_t)(obase + mi * 16 + l16) * CC + k0 + quad * 8);
            #pragma unroll
            for (int ni = 0; ni < 4; ++ni) {
                bf16x8 bfr = *(const bf16x8*)&xT[ni * 16 + l16][k0 + quad * 8];
                #pragma unroll
                for (int mi = 0; mi < 3; ++mi)
                    acc[mi][ni] = MFMA16(afr[mi], bfr, acc[mi][ni]);
            }
        }

        bf16_t* dst = (og < 2) ? qT : kT;
        #pragma unroll
        for (int mi = 0; mi < 3; ++mi)
            #pragma unroll
            for (int ni = 0; ni < 4; ++ni) {
                const int o0 = obase + mi * 16 + quad * 4;
                const int tl = t0 + ni * 16 + l16;
                U2 lo2, hi2;
                lo2.h[0] = (bf16_t)acc[mi][ni][0]; lo2.h[1] = (bf16_t)acc[mi][ni][1];
                hi2.h[0] = (bf16_t)acc[mi][ni][2]; hi2.h[1] = (bf16_t)acc[mi][ni][3];
                uint2 pk; pk.x = lo2.u; pk.y = hi2.u;
                *(uint2*)(dst + ((size_t)b * TT + tl) * CC + o0) = pk;
            }
    } else {
        // A = xT (m=t), B = W (n=o): regs span t -> vm[o][t]
        f32x4 acc[4][3];
        const f32x4 zero = {0.f, 0.f, 0.f, 0.f};
        #pragma unroll
        for (int mi = 0; mi < 4; ++mi)
            #pragma unroll
            for (int ni = 0; ni < 3; ++ni) acc[mi][ni] = zero;

        for (int k0 = 0; k0 < CC; k0 += 32) {
            bf16x8 bfr[3];
            #pragma unroll
            for (int ni = 0; ni < 3; ++ni)
                bfr[ni] = cvt8(W + (size_t)(obase + ni * 16 + l16) * CC + k0 + quad * 8);
            #pragma unroll
            for (int mi = 0; mi < 4; ++mi) {
                bf16x8 afr = *(const bf16x8*)&xT[mi * 16 + l16][k0 + quad * 8];
                #pragma unroll
                for (int ni = 0; ni < 3; ++ni)
                    acc[mi][ni] = MFMA16(afr, bfr[ni], acc[mi][ni]);
            }
        }

        #pragma unroll
        for (int mi = 0; mi < 4; ++mi)
            #pragma unroll
            for (int ni = 0; ni < 3; ++ni) {
                const int ol  = obase + ni * 16 + l16;
                const int tl0 = mi * 16 + quad * 4;
                U2 lo2, hi2;
                lo2.h[0] = (bf16_t)acc[mi][ni][0]; lo2.h[1] = (bf16_t)acc[mi][ni][1];
                hi2.h[0] = (bf16_t)acc[mi][ni][2]; hi2.h[1] = (bf16_t)acc[mi][ni][3];
                uint2 pk; pk.x = lo2.u; pk.y = hi2.u;
                *(uint2*)(vm + ((size_t)b * CC + ol) * TT + t0 + tl0) = pk;
            }

        // fused vrow: column sums over this block's 64 t, per o
        #pragma unroll
        for (int ni = 0; ni < 3; ++ni) {
            float s = 0.f;
            #pragma unroll
            for (int mi = 0; mi < 4; ++mi)
                #pragma unroll
                for (int r = 0; r < 4; ++r) s += acc[mi][ni][r];
            s += __shfl_xor(s, 16, 64);
            s += __shfl_xor(s, 32, 64);
            if (quad == 0)
                atomicAdd(&vrs[b * CC + obase + ni * 16 + l16], s);
        }
    }
}

// ---------------------------------------------------------------------------
// K2: fused attention. Block = (b = L&7 XCD-pinned, qt 64-q tile, th t-quarter
// of 256). 256 thr / 4 waves; each wave owns q16 = qt*64 + wid*16 with ALL 6
// heads (U[6][4] = 96 VGPR). Per 32-t tile:
//   scores: S_h^T = K_h . Q_h^T per head (lane: q=l16, t=blk*16+quad*4+r)
//   mix+exp: lane-local (36 SGPR coeffs), exact l/l2 in regs
//   P transpose: intra-wave ds_bpermute (8/head) -> PV A-frags; NO P LDS
//   PV: U[h][d] += P x V from LDS Vs
// LDS 72KB: Ks[32][384] single-buf | Vs[2][384][32] double-buf; swizzled <=2-way.
// 2 barriers/tile (staging only); K(t+1) issued after B1 (hidden by PV),
// V(t+1) issued at tile top (hidden by scores+mix). global_load_lds w=16,
// pre-swizzled global sources, linear LDS dests. 2 blocks/CU.
// Epilogue barrier-free (intra-wave shfl only).
// ---------------------------------------------------------------------------
__global__ __launch_bounds__(256, 2) void fused_attn(
    const bf16_t* __restrict__ qT,
    const bf16_t* __restrict__ kT,
    const bf16_t* __restrict__ vm,
    const float*  __restrict__ head_w,
    float* __restrict__ Up,      // [4][8][6][1024][64]
    float* __restrict__ lp,      // [4][48][1024]
    float* __restrict__ l2p)     // [4][48][1024]
{
    const int L  = blockIdx.x;
    const int b  = L & 7;              // XCD-pinned
    const int rr = L >> 3;
    const int qt = rr & 15;
    const int th = rr >> 4;            // 0..3
    const int T0 = th * 256;

    const int tid = threadIdx.x, lane = tid & 63, wid = tid >> 6;
    const int quad = lane >> 4, l16 = lane & 15;

    __shared__ __align__(16) bf16_t sm[36864];   // 72 KB: Ks 12288 | Vs 2x12288
    bf16_t* Ks = sm;

    // mix coefficients -> SGPRs
    float mixc[36];
    #pragma unroll
    for (int j = 0; j < 36; ++j) {
        const float v = 0.125f * head_w[j];
        mixc[j] = __uint_as_float(__builtin_amdgcn_readfirstlane(__float_as_uint(v)));
    }

    // staging offsets (pre-swizzled global src, linear LDS dst)
    int koff[6], voff[6], plds[6];
    #pragma unroll
    for (int i = 0; i < 6; ++i) {
        const int p = i * 256 + tid;              // 16B chunk index
        const int krow = p / 48, pch = p - krow * 48;
        const int kch = (pch & 56) | ((pch ^ krow) & 7);
        koff[i] = krow * CC + kch * 8;
        const int vrow = p >> 2;
        const int vch  = (p & 3) ^ ((vrow >> 1) & 3);
        voff[i] = vrow * TT + vch * 8;
        plds[i] = p * 16;                         // bytes (same for K and V)
    }
    const bf16_t* kTb = kT + ((size_t)b * TT + T0) * CC;
    const bf16_t* vmb = vm + (size_t)b * CC * TT + T0;
    const bf16_t* qp  = qT + ((size_t)b * TT + qt * 64 + wid * 16 + l16) * CC + quad * 8;
    char* KsB = (char*)sm;
    char* VsB = (char*)(sm + 12288);

    // prologue: stage tile 0
    #pragma unroll
    for (int i = 0; i < 6; ++i) {
        gload_lds16(kTb + koff[i], KsB + plds[i]);
        gload_lds16(vmb + voff[i], VsB + plds[i]);
    }

    f32x4 U[6][4];
    const f32x4 zero = {0.f, 0.f, 0.f, 0.f};
    #pragma unroll
    for (int h = 0; h < 6; ++h)
        #pragma unroll
        for (int d = 0; d < 4; ++d) U[h][d] = zero;
    float lacc[6]  = {0.f, 0.f, 0.f, 0.f, 0.f, 0.f};
    float l2acc[6] = {0.f, 0.f, 0.f, 0.f, 0.f, 0.f};

    const int  s3    = l16 & 7;
    const int  vswz  = (quad ^ ((l16 >> 1) & 3)) * 8 + l16 * 32;  // elems
    const int  addrA = ((quad & 1) * 32 + l16) * 4;               // src quad (quad&1)*2
    const int  addrB = addrA + 64;                                // src quad +1
    const bool qlo   = (quad < 2);

    __syncthreads();   // tile 0 staged (drains prologue loads)

    for (int tt = 0; tt < 8; ++tt) {
        // ---- issue V(t+1) -> other V buffer (hidden under scores+mix)
        if (tt < 7) {
            #pragma unroll
            for (int i = 0; i < 6; ++i)
                gload_lds16(vmb + (tt + 1) * 32 + voff[i],
                            VsB + ((tt + 1) & 1) * 24576 + plds[i]);
        }

        // ---- per-head scores: S_h^T (lane: q=l16, t=blk*16+quad*4+r)
        f32x4 S[6][2];
        bf16x8 qn0 = *(const bf16x8*)(qp);
        bf16x8 qn1 = *(const bf16x8*)(qp + 32);
        #pragma unroll
        for (int h = 0; h < 6; ++h) {
            bf16x8 q0 = qn0, q1 = qn1;
            if (h < 5) {
                qn0 = *(const bf16x8*)(qp + (h + 1) * 64);
                qn1 = *(const bf16x8*)(qp + (h + 1) * 64 + 32);
            }
            #pragma unroll
            for (int blk = 0; blk < 2; ++blk) {
                const bf16_t* Ar = Ks + (blk * 16 + l16) * CC + h * 64;
                bf16x8 a0 = *(const bf16x8*)(Ar + ((quad ^ s3) * 8));
                bf16x8 a1 = *(const bf16x8*)(Ar + (((4 + quad) ^ s3) * 8));
                f32x4 s = MFMA16(a0, q0, zero);
                S[h][blk] = MFMA16(a1, q1, s);
            }
        }

        // ---- mix + exp + l/l2 + intra-wave transpose -> PV A-frags
        bf16x8 pa[6];
        #pragma unroll
        for (int g = 0; g < 6; ++g) {
            unsigned int uu[2][2];
            #pragma unroll
            for (int blk = 0; blk < 2; ++blk) {
                f32x4 m = mixc[g * 6] * S[0][blk];
                #pragma unroll
                for (int h2 = 1; h2 < 6; ++h2) m += mixc[g * 6 + h2] * S[h2][blk];
                f32x4 pv;
                #pragma unroll
                for (int r = 0; r < 4; ++r) pv[r] = __expf(fminf(m[r], 60.0f));
                lacc[g]  += pv[0] + pv[1] + pv[2] + pv[3];
                l2acc[g] += pv[0] * pv[0] + pv[1] * pv[1] + pv[2] * pv[2] + pv[3] * pv[3];
                U2 lo, hi;
                lo.h[0] = (bf16_t)pv[0]; lo.h[1] = (bf16_t)pv[1];
                hi.h[0] = (bf16_t)pv[2]; hi.h[1] = (bf16_t)pv[3];
                uu[blk][0] = lo.u; uu[blk][1] = hi.u;
            }
            // dest u32 c holds t = quad*8 + 2c,2c+1; blk = quad>>1 (select),
            // src quad = (quad&1)*2 + (c>>1) (bpermute addr), pair = c&1.
            int x0 = __builtin_amdgcn_ds_bpermute(addrA, (int)uu[0][0]);
            int y0 = __builtin_amdgcn_ds_bpermute(addrA, (int)uu[1][0]);
            int x1 = __builtin_amdgcn_ds_bpermute(addrA, (int)uu[0][1]);
            int y1 = __builtin_amdgcn_ds_bpermute(addrA, (int)uu[1][1]);
            int x2 = __builtin_amdgcn_ds_bpermute(addrB, (int)uu[0][0]);
            int y2 = __builtin_amdgcn_ds_bpermute(addrB, (int)uu[1][0]);
            int x3 = __builtin_amdgcn_ds_bpermute(addrB, (int)uu[0][1]);
            int y3 = __builtin_amdgcn_ds_bpermute(addrB, (int)uu[1][1]);
            I4B c;
            c.i = (i32x4){qlo ? x0 : y0, qlo ? x1 : y1, qlo ? x2 : y2, qlo ? x3 : y3};
            pa[g] = c.v;
        }

        __syncthreads();   // B1: all score reads of Ks done

        // ---- issue K(t+1) into Ks (hidden under PV)
        if (tt < 7) {
            #pragma unroll
            for (int i = 0; i < 6; ++i)
                gload_lds16(kTb + (size_t)(tt + 1) * 32 * CC + koff[i], KsB + plds[i]);
        }

        // ---- PV: U[q][d] += P[q][t] * V[d][t]
        const bf16_t* Vb = sm + 12288 + (tt & 1) * 12288;
        #pragma unroll
        for (int h = 0; h < 6; ++h) {
            #pragma unroll
            for (int d = 0; d < 4; ++d) {
                bf16x8 bv = *(const bf16x8*)(Vb + (h * 64 + d * 16) * 32 + vswz);
                U[h][d] = MFMA16(pa[h], bv, U[h][d]);
            }
        }

        __syncthreads();   // B2: drain prefetches; PV reads done
    }

    // ---- l / l2: intra-wave reduce over quads (lane q = l16)
    #pragma unroll
    for (int g = 0; g < 6; ++g) {
        float l = lacc[g], l2 = l2acc[g];
        l  += __shfl_xor(l, 16, 64);  l  += __shfl_xor(l, 32, 64);
        l2 += __shfl_xor(l2, 16, 64); l2 += __shfl_xor(l2, 32, 64);
        if (quad == 0) {
            const size_t o = ((size_t)th * 48 + b * 6 + g) * TT + qt * 64 + wid * 16 + l16;
            lp[o] = l; l2p[o] = l2;
        }
    }

    // ---- partial U write (fp32, [th][b][g][q][d]); lane: q=quad*4+r, d=l16
    #pragma unroll
    for (int h = 0; h < 6; ++h) {
        float* Ub = Up + ((((size_t)th * 8 + b) * 6 + h) * TT + qt * 64 + wid * 16) * 64;
        #pragma unroll
        for (int d = 0; d < 4; ++d)
            #pragma unroll
            for (int r = 0; r < 4; ++r)
                Ub[(quad * 4 + r) * 64 + d * 16 + l16] = U[h][d][r];
    }
}

// ---------------------------------------------------------------------------
// K2b: merge 4 t-quarter partials: linv[bg][q] = 1/sum(l), sq[bg] = sum_q l2/l^2
// ---------------------------------------------------------------------------
__global__ __launch_bounds__(256) void stats_kernel(
    const float* __restrict__ lp, const float* __restrict__ l2p,
    float* __restrict__ linv, float* __restrict__ sq)
{
    const int bg = blockIdx.x, tid = threadIdx.x;
    float c = 0.f;
    for (int q = tid; q < TT; q += 256) {
        const float l  = lp [(size_t)bg * TT + q] + lp [(size_t)(48 + bg) * TT + q]
                       + lp [(size_t)(96 + bg) * TT + q] + lp [(size_t)(144 + bg) * TT + q];
        const float l2 = l2p[(size_t)bg * TT + q] + l2p[(size_t)(48 + bg) * TT + q]
                       + l2p[(size_t)(96 + bg) * TT + q] + l2p[(size_t)(144 + bg) * TT + q];
        const float inv = 1.0f / l;
        linv[bg * TT + q] = inv;
        c += l2 * inv * inv;
    }
    #pragma unroll
    for (int off = 1; off < 64; off <<= 1) c += __shfl_xor(c, off, 64);
    __shared__ float red[4];
    if ((tid & 63) == 0) red[tid >> 6] = c;
    __syncthreads();
    if (tid == 0) sq[bg] = red[0] + red[1] + red[2] + red[3];
}

// ---------------------------------------------------------------------------
// K3: projection + fused InstanceNorm affine + bias + transpose. fp32 weights.
//   Z[t'][c'] = Ac[h]*(sum_p Up[p][off]) * linv[off>>6] + Cc[h]*vrs[b][c']
// ---------------------------------------------------------------------------
__global__ __launch_bounds__(256) void proj_kernel(
    const float* __restrict__ Up,
    const float* __restrict__ linv,
    const float* __restrict__ vrs,
    const float* __restrict__ sumsq,
    const float* __restrict__ gamma,
    const float* __restrict__ beta,
    const float* __restrict__ projW,
    const float* __restrict__ projb,
    float* __restrict__ out)
{
    const int ts = blockIdx.x;
    const int b  = blockIdx.y;
    const int t0 = ts * 32;
    const int tid = threadIdx.x, lane = tid & 63, wid = tid >> 6;
    const int quad = lane >> 4, l16 = lane & 15;

    __shared__ float Ac[6], Cc[6], pb[CC];
    if (tid < 6) {
        const float ss  = sumsq[b * NHH + tid];
        const float var = fmaxf(ss - 1.0f, 0.0f) * (1.0f / 1048576.0f);
        const float a   = gamma[tid] * rsqrtf(var + 1e-5f);
        Ac[tid] = a;
        Cc[tid] = beta[tid] - a * (1.0f / 1024.0f);
    }
    for (int i = tid; i < CC; i += 256) pb[i] = projb[i];
    __syncthreads();

    f32x4 acc[6][2];
    const f32x4 zero = {0.f, 0.f, 0.f, 0.f};
    #pragma unroll
    for (int mi = 0; mi < 6; ++mi)
        #pragma unroll
        for (int ni = 0; ni < 2; ++ni) acc[mi][ni] = zero;

    constexpr size_t PST = (size_t)BB * NHH * TT * 64;
    const float* Ub = Up + (size_t)b * (NHH * TT * 64);
    for (int k0 = 0; k0 < CC; k0 += 32) {
        bf16x8 bfr[2];
        #pragma unroll
        for (int ni = 0; ni < 2; ++ni) {
            const int tl = t0 + ni * 16 + l16;
            const int baseoff = tl * CC + k0 + quad * 8;
            const int hh = baseoff >> 16;                 // constant over j
            const float li = linv[b * 6144 + (baseoff >> 6)];
            const float A  = Ac[hh];
            const float Cb = Cc[hh];
            f32x4 s0 = zero, s1 = zero;
            #pragma unroll
            for (int p = 0; p < 4; ++p) {
                s0 += *(const f32x4*)(Ub + p * PST + baseoff);
                s1 += *(const f32x4*)(Ub + p * PST + baseoff + 4);
            }
            U8 z;
            #pragma unroll
            for (int j = 0; j < 8; ++j) {
                const int d = (baseoff + j) & 63;
                const float uv = ((j < 4) ? s0[j] : s1[j - 4]) * li;
                z.h[j] = (bf16_t)(A * uv + Cb * vrs[b * CC + hh * 64 + d]);
            }
            bfr[ni] = *(const bf16x8*)&z;
        }
        #pragma unroll
        for (int mi = 0; mi < 6; ++mi) {
            const int o = wid * 96 + mi * 16 + l16;
            bf16x8 afr = cvt8(projW + (size_t)o * CC + k0 + quad * 8);
            #pragma unroll
            for (int ni = 0; ni < 2; ++ni)
                acc[mi][ni] = MFMA16(afr, bfr[ni], acc[mi][ni]);
        }
    }

    #pragma unroll
    for (int mi = 0; mi < 6; ++mi)
        #pragma unroll
        for (int ni = 0; ni < 2; ++ni)
            #pragma unroll
            for (int r = 0; r < 4; ++r) {
                const int o  = wid * 96 + mi * 16 + quad * 4 + r;
                const int tl = t0 + ni * 16 + l16;
                out[((size_t)b * CC + o) * TT + tl] = acc[mi][ni][r] + pb[o];
            }
}

// ---------------------------------------------------------------------------
extern "C" void kernel_launch(void* const* d_in, const int* in_sizes, int n_in,
                              void* d_out, int out_size, void* d_ws, size_t ws_size,
                              hipStream_t stream)
{
    float* outp = (float*)d_out;
    char* ws = (char*)d_ws;

    size_t off = 0;
    auto alloc = [&](size_t bytes) {
        void* p = ws + off;
        off += (bytes + 255) & ~(size_t)255;
        return p;
    };

    const size_t szT = (size_t)BB * TT * CC * sizeof(bf16_t);   // 6.29 MB

    bf16_t* qTb = (bf16_t*)alloc(szT);
    bf16_t* kTb = (bf16_t*)alloc(szT);
    bf16_t* vmb = (bf16_t*)alloc(szT);
    float*  Uh  = (float*)alloc((size_t)4 * BB * NHH * TT * 64 * sizeof(float)); // 50.3 MB
    float*  lpb = (float*)alloc((size_t)4 * 48 * TT * sizeof(float));
    float*  l2b = (float*)alloc((size_t)4 * 48 * TT * sizeof(float));
    float*  lv  = (float*)alloc((size_t)48 * TT * sizeof(float));
    float*  vr  = (float*)alloc((size_t)BB * CC * sizeof(float));
    float*  sq  = (float*)alloc(48 * sizeof(float));

    hipMemsetAsync(vr, 0, (size_t)BB * CC * sizeof(float), stream);
    qkv_kernel<<<dim3(6, 16, 8), 256, 0, stream>>>(
        (const float*)d_in[0], (const float*)d_in[1], (const float*)d_in[2],
        (const float*)d_in[3], qTb, kTb, vmb, vr);
    fused_attn<<<512, 256, 0, stream>>>(
        qTb, kTb, vmb, (const float*)d_in[4], Uh, lpb, l2b);
    stats_kernel<<<48, 256, 0, stream>>>(lpb, l2b, lv, sq);
    proj_kernel<<<dim3(32, 8), 256, 0, stream>>>(
        Uh, lv, vr, sq, (const float*)d_in[5], (const float*)d_in[6],
        (const float*)d_in[7], (const float*)d_in[8], outp);
}

// Round 3
// 246.368 us; speedup vs baseline: 1.3932x; 1.3932x over previous
//
#include <hip/hip_runtime.h>
#include <hip/hip_bf16.h>
#include <cstdint>

typedef __bf16 bf16_t;
typedef __bf16 bf16x8 __attribute__((ext_vector_type(8)));
typedef float  f32x4  __attribute__((ext_vector_type(4)));
typedef int    i32x4  __attribute__((ext_vector_type(4)));

#define MFMA16(a, b, c) __builtin_amdgcn_mfma_f32_16x16x32_bf16((a), (b), (c), 0, 0, 0)

constexpr int BB = 8, CC = 384, NHH = 6, TT = 1024;

union U8 { uint4 u; bf16_t h[8]; };
union U2 { unsigned int u; bf16_t h[2]; };
union I4B { i32x4 i; bf16x8 v; };

static __device__ __forceinline__ void gload_lds16(const void* g, void* l) {
    __builtin_amdgcn_global_load_lds((const __attribute__((address_space(1))) void*)g,
                                     (__attribute__((address_space(3))) void*)l, 16, 0, 0);
}

// load 8 consecutive fp32 -> bf16x8
static __device__ __forceinline__ bf16x8 cvt8(const float* p) {
    f32x4 a = *(const f32x4*)p, b = *(const f32x4*)(p + 4);
    U8 o;
    #pragma unroll
    for (int j = 0; j < 4; ++j) { o.h[j] = (bf16_t)a[j]; o.h[4 + j] = (bf16_t)b[j]; }
    return *(bf16x8*)&o;
}

// ---------------------------------------------------------------------------
// K1: QKV projection from fp32 inputs (cast fused). Also computes
// vrs[b][o] = sum_t v[b][o][t] via shuffle-reduce + atomics (vrow fused).
// ---------------------------------------------------------------------------
__global__ __launch_bounds__(256) void qkv_kernel(
    const float* __restrict__ x,
    const float* __restrict__ Wq,
    const float* __restrict__ Wk,
    const float* __restrict__ Wv,
    bf16_t* __restrict__ qT,
    bf16_t* __restrict__ kT,
    bf16_t* __restrict__ vm,
    float*  __restrict__ vrs)
{
    const int og = blockIdx.x;        // 0,1:q  2,3:k  4,5:v
    const int tt = blockIdx.y;
    const int b  = blockIdx.z;
    const int t0 = tt * 64;
    const int tid  = threadIdx.x;
    const int lane = tid & 63;
    const int wid  = tid >> 6;
    const int quad = lane >> 4;
    const int l16  = lane & 15;

    __shared__ __align__(16) bf16_t xT[64][CC + 8];

    {
        const float* xb = x + (size_t)b * CC * TT;
        const int tq = tid & 7;
        const int cp = tid >> 3;
        #pragma unroll
        for (int pass = 0; pass < 6; ++pass) {
            const int c = (pass * 32 + cp) * 2;
            const float* r0 = xb + (size_t)c * TT + t0 + tq * 8;
            const float* r1 = r0 + TT;
            f32x4 a0 = *(const f32x4*)r0, a1 = *(const f32x4*)(r0 + 4);
            f32x4 b0 = *(const f32x4*)r1, b1 = *(const f32x4*)(r1 + 4);
            #pragma unroll
            for (int j = 0; j < 8; ++j) {
                U2 p;
                p.h[0] = (bf16_t)((j < 4) ? a0[j] : a1[j - 4]);
                p.h[1] = (bf16_t)((j < 4) ? b0[j] : b1[j - 4]);
                *(unsigned int*)&xT[tq * 8 + j][c] = p.u;
            }
        }
    }
    __syncthreads();

    const float* W = (og < 2) ? Wq : (og < 4) ? Wk : Wv;
    const int obase = (og & 1) * 192 + wid * 48;

    if (og < 4) {
        f32x4 acc[3][4];
        const f32x4 zero = {0.f, 0.f, 0.f, 0.f};
        #pragma unroll
        for (int mi = 0; mi < 3; ++mi)
            #pragma unroll
            for (int ni = 0; ni < 4; ++ni) acc[mi][ni] = zero;

        for (int k0 = 0; k0 < CC; k0 += 32) {
            bf16x8 afr[3];
            #pragma unroll
            for (int mi = 0; mi < 3; ++mi)
                afr[mi] = cvt8(W + (size_t)(obase + mi * 16 + l16) * CC + k0 + quad * 8);
            #pragma unroll
            for (int ni = 0; ni < 4; ++ni) {
                bf16x8 bfr = *(const bf16x8*)&xT[ni * 16 + l16][k0 + quad * 8];
                #pragma unroll
                for (int mi = 0; mi < 3; ++mi)
                    acc[mi][ni] = MFMA16(afr[mi], bfr, acc[mi][ni]);
            }
        }

        bf16_t* dst = (og < 2) ? qT : kT;
        #pragma unroll
        for (int mi = 0; mi < 3; ++mi)
            #pragma unroll
            for (int ni = 0; ni < 4; ++ni) {
                const int o0 = obase + mi * 16 + quad * 4;
                const int tl = t0 + ni * 16 + l16;
                U2 lo2, hi2;
                lo2.h[0] = (bf16_t)acc[mi][ni][0]; lo2.h[1] = (bf16_t)acc[mi][ni][1];
                hi2.h[0] = (bf16_t)acc[mi][ni][2]; hi2.h[1] = (bf16_t)acc[mi][ni][3];
                uint2 pk; pk.x = lo2.u; pk.y = hi2.u;
                *(uint2*)(dst + ((size_t)b * TT + tl) * CC + o0) = pk;
            }
    } else {
        f32x4 acc[4][3];
        const f32x4 zero = {0.f, 0.f, 0.f, 0.f};
        #pragma unroll
        for (int mi = 0; mi < 4; ++mi)
            #pragma unroll
            for (int ni = 0; ni < 3; ++ni) acc[mi][ni] = zero;

        for (int k0 = 0; k0 < CC; k0 += 32) {
            bf16x8 bfr[3];
            #pragma unroll
            for (int ni = 0; ni < 3; ++ni)
                bfr[ni] = cvt8(W + (size_t)(obase + ni * 16 + l16) * CC + k0 + quad * 8);
            #pragma unroll
            for (int mi = 0; mi < 4; ++mi) {
                bf16x8 afr = *(const bf16x8*)&xT[mi * 16 + l16][k0 + quad * 8];
                #pragma unroll
                for (int ni = 0; ni < 3; ++ni)
                    acc[mi][ni] = MFMA16(afr, bfr[ni], acc[mi][ni]);
            }
        }

        #pragma unroll
        for (int mi = 0; mi < 4; ++mi)
            #pragma unroll
            for (int ni = 0; ni < 3; ++ni) {
                const int ol  = obase + ni * 16 + l16;
                const int tl0 = mi * 16 + quad * 4;
                U2 lo2, hi2;
                lo2.h[0] = (bf16_t)acc[mi][ni][0]; lo2.h[1] = (bf16_t)acc[mi][ni][1];
                hi2.h[0] = (bf16_t)acc[mi][ni][2]; hi2.h[1] = (bf16_t)acc[mi][ni][3];
                uint2 pk; pk.x = lo2.u; pk.y = hi2.u;
                *(uint2*)(vm + ((size_t)b * CC + ol) * TT + t0 + tl0) = pk;
            }

        #pragma unroll
        for (int ni = 0; ni < 3; ++ni) {
            float s = 0.f;
            #pragma unroll
            for (int mi = 0; mi < 4; ++mi)
                #pragma unroll
                for (int r = 0; r < 4; ++r) s += acc[mi][ni][r];
            s += __shfl_xor(s, 16, 64);
            s += __shfl_xor(s, 32, 64);
            if (quad == 0)
                atomicAdd(&vrs[b * CC + obase + ni * 16 + l16], s);
        }
    }
}

// ---------------------------------------------------------------------------
// K2: fused attention, full-t per block (NO U partials).
// Grid 256 = 8 b (XCD-pinned) x 32 q-tiles of 32 q. 256 thr / 4 waves:
// wave = (qg = wid&1: 16-q group, ts = wid>>1: 32-t slice of each 64-t tile).
// Per 64-t tile (16 tiles):
//   top:    issue V(t) -> Vs (single buf; prev PV reads done at prior B2)
//   scores: 6 per-head S (K=64 segmented), Q persistent in 48 VGPRs
//   mix+exp+bpermute-transpose -> pa (round-2 proven, verbatim)
//   B1 (drains V(t); Ks reads done) ; issue K(t+1)
//   PV: U[6][4] += pa x Vs      ; B2 (drains K(t+1); Vs reads done)
// Epilogue: merge U/l/l2 across ts-pairs in LDS, linv in-block, Uhat fp32
// pre-normalized (nontemporal store), sumsq via atomics. LDS 96 KB.
// ---------------------------------------------------------------------------
__global__ __launch_bounds__(256, 1) void fused_attn(
    const bf16_t* __restrict__ qT,
    const bf16_t* __restrict__ kT,
    const bf16_t* __restrict__ vm,
    const float*  __restrict__ head_w,
    float* __restrict__ Uhat,    // [8][6][1024][64], pre-divided by l
    float* __restrict__ sq)      // [48] sum_q l2/l^2
{
    const int L  = blockIdx.x;
    const int b  = L & 7;              // XCD-pinned
    const int qt = L >> 3;             // 0..31

    const int tid = threadIdx.x, lane = tid & 63, wid = tid >> 6;
    const int quad = lane >> 4, l16 = lane & 15;
    const int qg = wid & 1, ts = wid >> 1;

    __shared__ __align__(16) bf16_t sm[49152];   // 96 KB: Ks[64][384] | Vs[384][64]
    bf16_t* Ks = sm;

    // mix coefficients -> SGPRs
    float mixc[36];
    #pragma unroll
    for (int j = 0; j < 36; ++j) {
        const float v = 0.125f * head_w[j];
        mixc[j] = __uint_as_float(__builtin_amdgcn_readfirstlane(__float_as_uint(v)));
    }

    // persistent Q fragments: rows q = qt*32 + qg*16 + l16
    bf16x8 qf[6][2];
    {
        const bf16_t* qp = qT + ((size_t)b * TT + qt * 32 + qg * 16 + l16) * CC + quad * 8;
        #pragma unroll
        for (int h = 0; h < 6; ++h)
            #pragma unroll
            for (int k2 = 0; k2 < 2; ++k2)
                qf[h][k2] = *(const bf16x8*)(qp + h * 64 + k2 * 32);
    }

    // staging: pre-swizzled global src, linear LDS dst. 3072 16B-chunks each.
    int koff[12], voff[12];
    #pragma unroll
    for (int i = 0; i < 12; ++i) {
        const int f = i * 256 + tid;
        const int krow = f / 48, kc = f - krow * 48;
        koff[i] = krow * CC + ((kc & 56) | ((kc ^ krow) & 7)) * 8;
        const int vrow = f >> 3, vc = f & 7;
        voff[i] = vrow * TT + ((vc ^ (vrow & 7)) * 8);
    }
    const bf16_t* kTb = kT + (size_t)b * TT * CC;
    const bf16_t* vmb = vm + (size_t)b * CC * TT;
    char* KsB = (char*)sm;
    char* VsB = (char*)sm + 49152;     // elem 24576
    const int ldst = tid * 16;

    // prologue: stage K tile 0
    #pragma unroll
    for (int i = 0; i < 12; ++i)
        gload_lds16(kTb + koff[i], KsB + i * 4096 + ldst);

    f32x4 U[6][4];
    const f32x4 zero = {0.f, 0.f, 0.f, 0.f};
    #pragma unroll
    for (int h = 0; h < 6; ++h)
        #pragma unroll
        for (int d = 0; d < 4; ++d) U[h][d] = zero;
    float lacc[6]  = {0.f, 0.f, 0.f, 0.f, 0.f, 0.f};
    float l2acc[6] = {0.f, 0.f, 0.f, 0.f, 0.f, 0.f};

    const int  s3    = l16 & 7;
    const int  rbase = ts * 32;
    const int  addrA = ((quad & 1) * 32 + l16) * 4;
    const int  addrB = addrA + 64;
    const bool qlo   = (quad < 2);

    __syncthreads();   // K tile 0 staged

    for (int tt = 0; tt < 16; ++tt) {
        // ---- issue V(t) (Vs reads of tile t-1 completed at prior B2)
        #pragma unroll
        for (int i = 0; i < 12; ++i)
            gload_lds16(vmb + tt * 64 + voff[i], VsB + i * 4096 + ldst);

        // ---- per-head scores: lane (q = l16, t = rbase + blk*16 + quad*4 + r)
        f32x4 S[6][2];
        #pragma unroll
        for (int h = 0; h < 6; ++h) {
            #pragma unroll
            for (int blk = 0; blk < 2; ++blk) {
                const bf16_t* Ar = Ks + (size_t)(rbase + blk * 16 + l16) * CC + h * 64;
                bf16x8 a0 = *(const bf16x8*)(Ar + ((quad ^ s3) * 8));
                bf16x8 a1 = *(const bf16x8*)(Ar + (((4 + quad) ^ s3) * 8));
                f32x4 s = MFMA16(a0, qf[h][0], zero);
                S[h][blk] = MFMA16(a1, qf[h][1], s);
            }
        }

        // ---- mix + exp + l/l2 + intra-wave transpose -> PV A-frags (proven)
        bf16x8 pa[6];
        #pragma unroll
        for (int g = 0; g < 6; ++g) {
            unsigned int uu[2][2];
            #pragma unroll
            for (int blk = 0; blk < 2; ++blk) {
                f32x4 m = mixc[g * 6] * S[0][blk];
                #pragma unroll
                for (int h2 = 1; h2 < 6; ++h2) m += mixc[g * 6 + h2] * S[h2][blk];
                f32x4 pv;
                #pragma unroll
                for (int r = 0; r < 4; ++r) pv[r] = __expf(fminf(m[r], 60.0f));
                lacc[g]  += pv[0] + pv[1] + pv[2] + pv[3];
                l2acc[g] += pv[0] * pv[0] + pv[1] * pv[1] + pv[2] * pv[2] + pv[3] * pv[3];
                U2 lo, hi;
                lo.h[0] = (bf16_t)pv[0]; lo.h[1] = (bf16_t)pv[1];
                hi.h[0] = (bf16_t)pv[2]; hi.h[1] = (bf16_t)pv[3];
                uu[blk][0] = lo.u; uu[blk][1] = hi.u;
            }
            int x0 = __builtin_amdgcn_ds_bpermute(addrA, (int)uu[0][0]);
            int y0 = __builtin_amdgcn_ds_bpermute(addrA, (int)uu[1][0]);
            int x1 = __builtin_amdgcn_ds_bpermute(addrA, (int)uu[0][1]);
            int y1 = __builtin_amdgcn_ds_bpermute(addrA, (int)uu[1][1]);
            int x2 = __builtin_amdgcn_ds_bpermute(addrB, (int)uu[0][0]);
            int y2 = __builtin_amdgcn_ds_bpermute(addrB, (int)uu[1][0]);
            int x3 = __builtin_amdgcn_ds_bpermute(addrB, (int)uu[0][1]);
            int y3 = __builtin_amdgcn_ds_bpermute(addrB, (int)uu[1][1]);
            I4B c;
            c.i = (i32x4){qlo ? x0 : y0, qlo ? x1 : y1, qlo ? x2 : y2, qlo ? x3 : y3};
            pa[g] = c.v;
        }

        __syncthreads();   // B1: Ks reads done; V(t) drained

        // ---- issue K(t+1) (hidden under PV)
        if (tt < 15) {
            #pragma unroll
            for (int i = 0; i < 12; ++i)
                gload_lds16(kTb + (size_t)(tt + 1) * 64 * CC + koff[i], KsB + i * 4096 + ldst);
        }

        // ---- PV: U[q][d] += P[q][t] * V[d][t] over wave's 32-t slice
        const bf16_t* Vb = sm + 24576;
        #pragma unroll
        for (int h = 0; h < 6; ++h) {
            #pragma unroll
            for (int n2 = 0; n2 < 4; ++n2) {
                bf16x8 bv = *(const bf16x8*)(Vb + (size_t)(h * 64 + n2 * 16 + l16) * 64
                                             + (((ts * 4 + quad) ^ s3) * 8));
                U[h][n2] = MFMA16(pa[h], bv, U[h][n2]);
            }
        }

        __syncthreads();   // B2: K(t+1) drained; Vs reads done
    }

    // ---- epilogue: merge the two ts waves per qg in LDS
    float* MB   = (float*)sm;          // [2*6*16][64] = 12288 floats (Ks region, dead)
    float* Lh   = MB + 12288;          // [2][6][16]
    float* L2h  = Lh + 192;            // [2][6][16]
    float* lnvT = L2h + 192;           // [2][6][16]

    float lrow[6], l2row[6];
    #pragma unroll
    for (int g = 0; g < 6; ++g) {
        float l = lacc[g], l2 = l2acc[g];
        l  += __shfl_xor(l, 16, 64);  l  += __shfl_xor(l, 32, 64);
        l2 += __shfl_xor(l2, 16, 64); l2 += __shfl_xor(l2, 32, 64);
        lrow[g] = l; l2row[g] = l2;
    }

    if (ts == 1) {
        #pragma unroll
        for (int h = 0; h < 6; ++h)
            #pragma unroll
            for (int n2 = 0; n2 < 4; ++n2)
                #pragma unroll
                for (int r = 0; r < 4; ++r)
                    MB[(size_t)((qg * 6 + h) * 16 + quad * 4 + r) * 64 + n2 * 16 + l16] = U[h][n2][r];
        if (quad == 0) {
            #pragma unroll
            for (int g = 0; g < 6; ++g) {
                Lh [(qg * 6 + g) * 16 + l16] = lrow[g];
                L2h[(qg * 6 + g) * 16 + l16] = l2row[g];
            }
        }
    }
    __syncthreads();

    if (ts == 0) {
        float linvq[6];
        #pragma unroll
        for (int g = 0; g < 6; ++g) {
            lrow[g]  += Lh [(qg * 6 + g) * 16 + l16];
            l2row[g] += L2h[(qg * 6 + g) * 16 + l16];
            linvq[g] = 1.0f / lrow[g];
        }
        // sumsq contribution (per g, summed over this wave's 16 q)
        #pragma unroll
        for (int g = 0; g < 6; ++g) {
            float c = l2row[g] * linvq[g] * linvq[g];
            c += __shfl_xor(c, 1, 64); c += __shfl_xor(c, 2, 64);
            c += __shfl_xor(c, 4, 64); c += __shfl_xor(c, 8, 64);
            if (lane == 0) atomicAdd(&sq[b * NHH + g], c);
        }
        if (quad == 0) {
            #pragma unroll
            for (int g = 0; g < 6; ++g)
                lnvT[(qg * 6 + g) * 16 + l16] = linvq[g];
        }
        // merge + normalize + nontemporal store Uhat[b][h][q][d]
        #pragma unroll
        for (int h = 0; h < 6; ++h) {
            float* Ub = Uhat + ((size_t)(b * NHH + h) * TT + qt * 32 + qg * 16) * 64;
            #pragma unroll
            for (int n2 = 0; n2 < 4; ++n2)
                #pragma unroll
                for (int r = 0; r < 4; ++r) {
                    const float u = U[h][n2][r]
                        + MB[(size_t)((qg * 6 + h) * 16 + quad * 4 + r) * 64 + n2 * 16 + l16];
                    const float li = lnvT[(qg * 6 + h) * 16 + quad * 4 + r];
                    __builtin_nontemporal_store(u * li,
                        Ub + (size_t)(quad * 4 + r) * 64 + n2 * 16 + l16);
                }
        }
    }
}

// ---------------------------------------------------------------------------
// K3: projection + fused InstanceNorm affine + bias + transpose.
//   Z[t'][c'] = Ac[h]*Uhat_flat[off] + Cc[h]*vrs[b][c'], off = t'*384 + c'
// ---------------------------------------------------------------------------
__global__ __launch_bounds__(256) void proj_kernel(
    const float* __restrict__ Uhat,
    const float* __restrict__ vrs,
    const float* __restrict__ sumsq,
    const float* __restrict__ gamma,
    const float* __restrict__ beta,
    const float* __restrict__ projW,
    const float* __restrict__ projb,
    float* __restrict__ out)
{
    const int ts = blockIdx.x;
    const int b  = blockIdx.y;
    const int t0 = ts * 32;
    const int tid = threadIdx.x, lane = tid & 63, wid = tid >> 6;
    const int quad = lane >> 4, l16 = lane & 15;

    __shared__ float Ac[6], Cc[6], pb[CC];
    if (tid < 6) {
        const float ss  = sumsq[b * NHH + tid];
        const float var = fmaxf(ss - 1.0f, 0.0f) * (1.0f / 1048576.0f);
        const float a   = gamma[tid] * rsqrtf(var + 1e-5f);
        Ac[tid] = a;
        Cc[tid] = beta[tid] - a * (1.0f / 1024.0f);
    }
    for (int i = tid; i < CC; i += 256) pb[i] = projb[i];
    __syncthreads();

    f32x4 acc[6][2];
    const f32x4 zero = {0.f, 0.f, 0.f, 0.f};
    #pragma unroll
    for (int mi = 0; mi < 6; ++mi)
        #pragma unroll
        for (int ni = 0; ni < 2; ++ni) acc[mi][ni] = zero;

    const float* Ub = Uhat + (size_t)b * TT * CC;
    for (int k0 = 0; k0 < CC; k0 += 32) {
        bf16x8 bfr[2];
        #pragma unroll
        for (int ni = 0; ni < 2; ++ni) {
            const int tl = t0 + ni * 16 + l16;
            const int baseoff = tl * CC + k0 + quad * 8;
            const int hh = baseoff >> 16;                 // constant over j
            const float A  = Ac[hh];
            const float Cb = Cc[hh];
            f32x4 u0 = __builtin_nontemporal_load((const f32x4*)(Ub + baseoff));
            f32x4 u1 = __builtin_nontemporal_load((const f32x4*)(Ub + baseoff + 4));
            U8 z;
            #pragma unroll
            for (int j = 0; j < 8; ++j) {
                const int d = (baseoff + j) & 63;
                const float uv = (j < 4) ? u0[j] : u1[j - 4];
                z.h[j] = (bf16_t)(A * uv + Cb * vrs[b * CC + hh * 64 + d]);
            }
            bfr[ni] = *(const bf16x8*)&z;
        }
        #pragma unroll
        for (int mi = 0; mi < 6; ++mi) {
            const int o = wid * 96 + mi * 16 + l16;
            bf16x8 afr = cvt8(projW + (size_t)o * CC + k0 + quad * 8);
            #pragma unroll
            for (int ni = 0; ni < 2; ++ni)
                acc[mi][ni] = MFMA16(afr, bfr[ni], acc[mi][ni]);
        }
    }

    #pragma unroll
    for (int mi = 0; mi < 6; ++mi)
        #pragma unroll
        for (int ni = 0; ni < 2; ++ni)
            #pragma unroll
            for (int r = 0; r < 4; ++r) {
                const int o  = wid * 96 + mi * 16 + quad * 4 + r;
                const int tl = t0 + ni * 16 + l16;
                out[((size_t)b * CC + o) * TT + tl] = acc[mi][ni][r] + pb[o];
            }
}

// ---------------------------------------------------------------------------
extern "C" void kernel_launch(void* const* d_in, const int* in_sizes, int n_in,
                              void* d_out, int out_size, void* d_ws, size_t ws_size,
                              hipStream_t stream)
{
    float* outp = (float*)d_out;
    char* ws = (char*)d_ws;

    size_t off = 0;
    auto alloc = [&](size_t bytes) {
        void* p = ws + off;
        off += (bytes + 255) & ~(size_t)255;
        return p;
    };

    const size_t szT = (size_t)BB * TT * CC * sizeof(bf16_t);   // 6.29 MB

    bf16_t* qTb = (bf16_t*)alloc(szT);
    bf16_t* kTb = (bf16_t*)alloc(szT);
    bf16_t* vmb = (bf16_t*)alloc(szT);
    float*  Uh  = (float*)alloc((size_t)BB * NHH * TT * 64 * sizeof(float));  // 12.6 MB
    float*  vr  = (float*)alloc((size_t)BB * CC * sizeof(float));
    float*  sq  = (float*)alloc(48 * sizeof(float));

    hipMemsetAsync(vr, 0, (size_t)BB * CC * sizeof(float), stream);
    hipMemsetAsync(sq, 0, 48 * sizeof(float), stream);
    qkv_kernel<<<dim3(6, 16, 8), 256, 0, stream>>>(
        (const float*)d_in[0], (const float*)d_in[1], (const float*)d_in[2],
        (const float*)d_in[3], qTb, kTb, vmb, vr);
    fused_attn<<<256, 256, 0, stream>>>(
        qTb, kTb, vmb, (const float*)d_in[4], Uh, sq);
    proj_kernel<<<dim3(32, 8), 256, 0, stream>>>(
        Uh, vr, sq, (const float*)d_in[5], (const float*)d_in[6],
        (const float*)d_in[7], (const float*)d_in[8], outp);
}